// Round 1
// baseline (410.732 us; speedup 1.0000x reference)
//
#include <hip/hip_runtime.h>
#include <hip/hip_bf16.h>
#include <math.h>

typedef __bf16 bf16x8 __attribute__((ext_vector_type(8)));
typedef unsigned short u16x8 __attribute__((ext_vector_type(8)));
typedef float f32x4 __attribute__((ext_vector_type(4)));

#define BATCH 32768
#define NFFT 1024
#define LDA 136            // padded LDS row stride (bf16 elems): 128 + 8
#define ROWS_PER_WG 16     // batch rows per workgroup -> M = 128
#define TWO_PI 6.283185307179586f

__device__ __forceinline__ unsigned short f2bf(float f) {
    __hip_bfloat16 h = __float2bfloat16(f);
    return __builtin_bit_cast(unsigned short, h);
}

// Setup: combine quantized halves into bf16 DFT matrices in workspace.
__global__ void build_w(const float* __restrict__ fru, const float* __restrict__ frl,
                        const float* __restrict__ fiu, const float* __restrict__ fil,
                        __hip_bfloat16* __restrict__ Wc, __hip_bfloat16* __restrict__ Ws)
{
    int i = blockIdx.x * 256 + threadIdx.x;
    if (i < 128 * 128) {
        Wc[i] = __float2bfloat16(fru[i] + frl[i]);
        Ws[i] = __float2bfloat16(fiu[i] + fil[i]);
    }
}

// Fused: de-interleave -> bf16 leaf-DFT GEMM (MFMA) -> 3 radix-2 stages in
// registers (stages 1-2 reg pairs, stage 3 shfl_xor 16) -> store.
__global__ __launch_bounds__(256, 2)
void fft_main(const float* __restrict__ x,
              const __hip_bfloat16* __restrict__ Wc,
              const __hip_bfloat16* __restrict__ Ws,
              float* __restrict__ outR,
              float* __restrict__ outI)
{
    __shared__ unsigned short As[128 * LDA];   // 34.8 KB

    const int t = threadIdx.x;
    const int rowbase = blockIdx.x * ROWS_PER_WG;

    // ---- stage A into LDS: A[m = brow*8 + g][n] = x[brow][bitrev3(g) + 8n] (bf16)
    {
        const int m = t >> 1;            // 0..127
        const int h = t & 1;             // n-half
        const int brow = m >> 3;
        const int g = m & 7;
        const int o = ((g & 1) << 2) | (g & 2) | ((g & 4) >> 2); // bitrev3
        const float* xr = x + (size_t)(rowbase + brow) * NFFT + o;
        #pragma unroll
        for (int jj = 0; jj < 8; ++jj) {
            u16x8 v;
            #pragma unroll
            for (int j = 0; j < 8; ++j)
                v[j] = f2bf(xr[(h * 64 + jj * 8 + j) * 8]);
            *(u16x8*)&As[m * LDA + h * 64 + jj * 8] = v;
        }
    }
    __syncthreads();

    const int wave = t >> 6;
    const int lane = t & 63;
    const int wr = wave >> 1;       // row 64-block
    const int wc = wave & 1;        // col 64-block
    const int lcol = lane & 15;
    const int quad = lane >> 4;

    f32x4 accR[4][4], accI[4][4];
    #pragma unroll
    for (int i = 0; i < 4; ++i)
        #pragma unroll
        for (int j = 0; j < 4; ++j) { accR[i][j] = (f32x4)0.0f; accI[i][j] = (f32x4)0.0f; }

    const unsigned short* WcU = (const unsigned short*)Wc;
    const unsigned short* WsU = (const unsigned short*)Ws;

    // ---- GEMM: R[m][k] = sum_n A[m][n] * W[k][n]   (W symmetric)
    #pragma unroll
    for (int ko = 0; ko < 4; ++ko) {
        bf16x8 af[4];
        #pragma unroll
        for (int rt = 0; rt < 4; ++rt) {
            u16x8 a = *(const u16x8*)&As[(wr * 64 + rt * 16 + lcol) * LDA + ko * 32 + quad * 8];
            af[rt] = __builtin_bit_cast(bf16x8, a);
        }
        #pragma unroll
        for (int nt = 0; nt < 4; ++nt) {
            const int kcol = wc * 64 + nt * 16 + lcol;
            bf16x8 bc = __builtin_bit_cast(bf16x8, *(const u16x8*)&WcU[kcol * 128 + ko * 32 + quad * 8]);
            bf16x8 bs = __builtin_bit_cast(bf16x8, *(const u16x8*)&WsU[kcol * 128 + ko * 32 + quad * 8]);
            #pragma unroll
            for (int rt = 0; rt < 4; ++rt) {
                accR[rt][nt] = __builtin_amdgcn_mfma_f32_16x16x32_bf16(af[rt], bc, accR[rt][nt], 0, 0, 0);
                accI[rt][nt] = __builtin_amdgcn_mfma_f32_16x16x32_bf16(af[rt], bs, accI[rt][nt], 0, 0, 0);
            }
        }
    }

    // ---- butterflies + store
    // acc tile rows: mloc = wr*64 + rt*16 + quad*4 + r;  brow = mloc>>3, g = mloc&7
    #pragma unroll
    for (int nt = 0; nt < 4; ++nt) {
        const int kk = wc * 64 + nt * 16 + lcol;   // leaf freq 0..127
        float c1, s1, c2a, s2a, c2b, s2b;
        __sincosf(-TWO_PI * (float)kk * (1.0f / 256.0f), &s1, &c1);
        __sincosf(-TWO_PI * (float)kk * (1.0f / 512.0f), &s2a, &c2a);
        __sincosf(-TWO_PI * (float)(kk + 128) * (1.0f / 512.0f), &s2b, &c2b);
        float c3[4], s3[4];
        #pragma unroll
        for (int r = 0; r < 4; ++r)
            __sincosf(-TWO_PI * (float)(kk + 128 * r) * (1.0f / 1024.0f), &s3[r], &c3[r]);

        #pragma unroll
        for (int rt = 0; rt < 4; ++rt) {
            float R[4], I[4];
            #pragma unroll
            for (int r = 0; r < 4; ++r) { R[r] = accR[rt][nt][r]; I[r] = accI[rt][nt][r]; }

            // stage 1: g-pairs (0,1),(2,3) -> regs (0,1),(2,3); tw = -2pi*kk/256
            {
                float tr = c1 * R[1] - s1 * I[1], ti = c1 * I[1] + s1 * R[1];
                float er = R[0], ei = I[0];
                R[0] = er + tr; I[0] = ei + ti; R[1] = er - tr; I[1] = ei - ti;
                tr = c1 * R[3] - s1 * I[3]; ti = c1 * I[3] + s1 * R[3];
                er = R[2]; ei = I[2];
                R[2] = er + tr; I[2] = ei + ti; R[3] = er - tr; I[3] = ei - ti;
            }
            // stage 2: (0,2) tw kk/512; (1,3) tw (kk+128)/512
            {
                float tr = c2a * R[2] - s2a * I[2], ti = c2a * I[2] + s2a * R[2];
                float er = R[0], ei = I[0];
                R[0] = er + tr; I[0] = ei + ti; R[2] = er - tr; I[2] = ei - ti;
                tr = c2b * R[3] - s2b * I[3]; ti = c2b * I[3] + s2b * R[3];
                er = R[1]; ei = I[1];
                R[1] = er + tr; I[1] = ei + ti; R[3] = er - tr; I[3] = ei - ti;
            }
            // stage 3: ev rows g=0..3 (even quads) pair with od rows g=4..7 (odd quads)
            const bool evq = (quad & 1) == 0;
            #pragma unroll
            for (int r = 0; r < 4; ++r) {
                float pr = __shfl_xor(R[r], 16, 64);
                float pi = __shfl_xor(I[r], 16, 64);
                float Rres, Ires;
                if (evq) {
                    float tr = c3[r] * pr - s3[r] * pi;
                    float ti = c3[r] * pi + s3[r] * pr;
                    Rres = R[r] + tr; Ires = I[r] + ti;
                } else {
                    float tr = c3[r] * R[r] - s3[r] * I[r];
                    float ti = c3[r] * I[r] + s3[r] * R[r];
                    Rres = pr - tr; Ires = pi - ti;
                }
                const int mloc = wr * 64 + rt * 16 + quad * 4 + r;
                const int brow = rowbase + (mloc >> 3);
                const int g = mloc & 7;
                const size_t idx = (size_t)brow * NFFT + g * 128 + kk;
                outR[idx] = Rres;
                outI[idx] = Ires;
            }
        }
    }
}

extern "C" void kernel_launch(void* const* d_in, const int* in_sizes, int n_in,
                              void* d_out, int out_size, void* d_ws, size_t ws_size,
                              hipStream_t stream)
{
    const float* x   = (const float*)d_in[0];
    const float* fru = (const float*)d_in[1];
    const float* frl = (const float*)d_in[2];
    const float* fiu = (const float*)d_in[3];
    const float* fil = (const float*)d_in[4];

    __hip_bfloat16* Wc = (__hip_bfloat16*)d_ws;
    __hip_bfloat16* Ws = Wc + 128 * 128;

    float* outR = (float*)d_out;
    float* outI = outR + (size_t)BATCH * NFFT;

    build_w<<<64, 256, 0, stream>>>(fru, frl, fiu, fil, Wc, Ws);
    fft_main<<<BATCH / ROWS_PER_WG, 256, 0, stream>>>(x, Wc, Ws, outR, outI);
}